// Round 1
// baseline (213.941 us; speedup 1.0000x reference)
//
#include <hip/hip_runtime.h>

#define M_NODES 4096
#define NN_NUM 16
#define G_NUM 4
#define IN_F 32
#define OUT_F 32
#define LOC_F 8
#define LHID 128
#define B_SZ 16
#define NPAIR (M_NODES * NN_NUM)      /* 65536 */
#define MM ((size_t)M_NODES * M_NODES) /* 16777216 */

// ---------------------------------------------------------------------------
// Kernel 1: fused per-pair MLP + softmax over the 16 neighbors of each node.
// attn[g*NPAIR + n], n = node*16 + neighbor (neighbors are consecutive lanes).
// ---------------------------------------------------------------------------
__global__ void attn_kernel(const float* __restrict__ maps,
                            const float* __restrict__ W1,
                            const float* __restrict__ b1,
                            const float* __restrict__ W2,
                            const float* __restrict__ b2,
                            float* __restrict__ attn) {
  const int g = blockIdx.y;
  __shared__ float sW1[LHID * LOC_F];
  __shared__ float sb1[LHID];
  __shared__ float sW2[LHID];
  const int t = threadIdx.x;
  for (int k = t; k < LHID * LOC_F; k += 256) sW1[k] = W1[g * LHID * LOC_F + k];
  if (t < LHID) { sb1[t] = b1[g * LHID + t]; sW2[t] = W2[g * LHID + t]; }
  __syncthreads();

  const int n = blockIdx.x * 256 + t;
  const float4 mA = *reinterpret_cast<const float4*>(maps + (size_t)n * LOC_F);
  const float4 mB = *reinterpret_cast<const float4*>(maps + (size_t)n * LOC_F + 4);

  float ctx = b2[g];
#pragma unroll 4
  for (int h = 0; h < LHID; ++h) {
    const float* w = &sW1[h * LOC_F];   // uniform address -> LDS broadcast
    float a = sb1[h];
    a = fmaf(w[0], mA.x, a); a = fmaf(w[1], mA.y, a);
    a = fmaf(w[2], mA.z, a); a = fmaf(w[3], mA.w, a);
    a = fmaf(w[4], mB.x, a); a = fmaf(w[5], mB.y, a);
    a = fmaf(w[6], mB.z, a); a = fmaf(w[7], mB.w, a);
    // tanh(a) = sign(a) * (1 - e^(-2|a|)) / (1 + e^(-2|a|)) -- stable
    const float e = __expf(-2.0f * fabsf(a));
    const float th = __builtin_copysignf((1.0f - e) / (1.0f + e), a);
    ctx = fmaf(sW2[h], th, ctx);
  }

  // softmax across the 16 lanes of this node (lanes n..n+15 in-wave)
  float mx = ctx;
#pragma unroll
  for (int m = 8; m >= 1; m >>= 1) mx = fmaxf(mx, __shfl_xor(mx, m, 64));
  const float e = __expf(ctx - mx);
  float s = e;
#pragma unroll
  for (int m = 8; m >= 1; m >>= 1) s += __shfl_xor(s, m, 64);
  attn[(size_t)g * NPAIR + n] = e / s;
}

// ---------------------------------------------------------------------------
// Duplicate resolution: numpy/XLA `.set` semantics = LAST occurrence wins.
// winner[pos] = max(n+1) over all n with L_idx[n]==pos (0 = empty).
// ---------------------------------------------------------------------------
__global__ void winner_kernel(const int* __restrict__ L_idx,
                              unsigned* __restrict__ winner) {
  const int n = blockIdx.x * 256 + threadIdx.x;
  atomicMax(&winner[(unsigned)L_idx[n]], (unsigned)(n + 1));
}

__global__ void hist_kernel(const int* __restrict__ L_idx,
                            const unsigned* __restrict__ winner,
                            unsigned* __restrict__ count) {
  const int n = blockIdx.x * 256 + threadIdx.x;
  const unsigned pos = (unsigned)L_idx[n];
  if (winner[pos] == (unsigned)(n + 1)) atomicAdd(&count[pos >> 12], 1u);
}

// Exclusive scan of count[4096] -> rowstart[4097]; rowfill = copy of rowstart.
__global__ void scan_kernel(const unsigned* __restrict__ count,
                            unsigned* __restrict__ rowstart,
                            unsigned* __restrict__ rowfill) {
  __shared__ unsigned sums[256];
  const int t = threadIdx.x;
  unsigned local[16];
  unsigned s = 0;
  for (int k = 0; k < 16; ++k) { local[k] = s; s += count[t * 16 + k]; }
  sums[t] = s;
  __syncthreads();
  for (int off = 1; off < 256; off <<= 1) {
    unsigned v = (t >= off) ? sums[t - off] : 0u;
    __syncthreads();
    sums[t] += v;
    __syncthreads();
  }
  const unsigned base = (t == 0) ? 0u : sums[t - 1];
  for (int k = 0; k < 16; ++k) {
    const unsigned rs = base + local[k];
    rowstart[t * 16 + k] = rs;
    rowfill[t * 16 + k] = rs;
  }
  if (t == 255) rowstart[M_NODES] = sums[255];
}

__global__ void fill_kernel(const int* __restrict__ L_idx,
                            const unsigned* __restrict__ winner,
                            unsigned* __restrict__ rowfill,
                            unsigned* __restrict__ csr) {
  const int n = blockIdx.x * 256 + threadIdx.x;
  const unsigned pos = (unsigned)L_idx[n];
  if (winner[pos] == (unsigned)(n + 1)) {
    const unsigned slot = atomicAdd(&rowfill[pos >> 12], 1u);
    csr[slot] = (unsigned)n;
  }
}

// ---------------------------------------------------------------------------
// y[g, b, j, o] = sum_f x[b, j, f] * Wx[g, f, o]    (4 x 16 x 4096 x 32)
// ---------------------------------------------------------------------------
__global__ void y_kernel(const float* __restrict__ x,
                         const float* __restrict__ Wx,
                         float* __restrict__ y) {
  const int g = blockIdx.y;
  __shared__ float sW[IN_F * OUT_F];
  const int t = threadIdx.x;
  for (int k = t; k < IN_F * OUT_F; k += 256) sW[k] = Wx[g * IN_F * OUT_F + k];
  __syncthreads();

  const int r = blockIdx.x * 8 + (t >> 5);  // r = b*M + j  in [0, 65536)
  const int o = t & 31;
  const float* xr = x + (size_t)r * IN_F;
  float acc = 0.0f;
#pragma unroll
  for (int f = 0; f < IN_F; ++f) acc = fmaf(xr[f], sW[f * OUT_F + o], acc);
  y[((size_t)g * NPAIR + r) * OUT_F + o] = acc;
}

// ---------------------------------------------------------------------------
// One block per output row i; 512 threads = (b in 0..15) x (o in 0..31).
// out[b, i, o] = bx[o] + sum_{n in row i} sum_g attn[g,n] * y[g, b, j_n, o]
// ---------------------------------------------------------------------------
__global__ void gather_kernel(const float* __restrict__ y,
                              const float* __restrict__ attn,
                              const int* __restrict__ L_idx,
                              const unsigned* __restrict__ rowstart,
                              const unsigned* __restrict__ csr,
                              const float* __restrict__ bx,
                              float* __restrict__ out) {
  const int i = blockIdx.x;
  const int t = threadIdx.x;
  const int b = t >> 5;
  const int o = t & 31;
  float acc = bx[o];
  const unsigned s0 = rowstart[i];
  const unsigned s1 = rowstart[i + 1];
  for (unsigned s = s0; s < s1; ++s) {
    const unsigned n = csr[s];
    const unsigned pos = (unsigned)L_idx[n];
    const int j = (int)(pos & (M_NODES - 1));
    const float a0 = attn[n];
    const float a1 = attn[1 * NPAIR + n];
    const float a2 = attn[2 * NPAIR + n];
    const float a3 = attn[3 * NPAIR + n];
    const float* yb = y + ((size_t)b * M_NODES + j) * OUT_F + o;
    acc = fmaf(a0, yb[0], acc);
    acc = fmaf(a1, yb[(size_t)1 * NPAIR * OUT_F], acc);
    acc = fmaf(a2, yb[(size_t)2 * NPAIR * OUT_F], acc);
    acc = fmaf(a3, yb[(size_t)3 * NPAIR * OUT_F], acc);
  }
  out[((size_t)b * M_NODES + i) * OUT_F + o] = acc;
}

// ---------------------------------------------------------------------------
extern "C" void kernel_launch(void* const* d_in, const int* in_sizes, int n_in,
                              void* d_out, int out_size, void* d_ws, size_t ws_size,
                              hipStream_t stream) {
  const float* x    = (const float*)d_in[0];
  const float* maps = (const float*)d_in[1];
  const int*   L_idx = (const int*)d_in[2];
  const float* W1   = (const float*)d_in[3];
  const float* b1   = (const float*)d_in[4];
  const float* W2   = (const float*)d_in[5];
  const float* b2   = (const float*)d_in[6];
  const float* Wx   = (const float*)d_in[7];
  const float* bx   = (const float*)d_in[8];
  float* out = (float*)d_out;

  // workspace layout (f32/u32 elements)
  float* attn = (float*)d_ws;                                   //  1 MB
  float* y = attn + (size_t)G_NUM * NPAIR;                      // 32 MB
  unsigned* winner = (unsigned*)(y + (size_t)G_NUM * B_SZ * M_NODES * OUT_F); // 64 MB
  unsigned* count = winner + MM;                                // 16 KB
  unsigned* rowstart = count + M_NODES;                         // 4097 u32
  unsigned* rowfill = rowstart + (M_NODES + 1);                 // 4096 u32
  unsigned* csr = rowfill + M_NODES;                            // 64K u32

  hipMemsetAsync(winner, 0, MM * sizeof(unsigned), stream);
  hipMemsetAsync(count, 0, M_NODES * sizeof(unsigned), stream);

  attn_kernel<<<dim3(NPAIR / 256, G_NUM), 256, 0, stream>>>(maps, W1, b1, W2, b2, attn);
  winner_kernel<<<NPAIR / 256, 256, 0, stream>>>(L_idx, winner);
  hist_kernel<<<NPAIR / 256, 256, 0, stream>>>(L_idx, winner, count);
  scan_kernel<<<1, 256, 0, stream>>>(count, rowstart, rowfill);
  fill_kernel<<<NPAIR / 256, 256, 0, stream>>>(L_idx, winner, rowfill, csr);
  y_kernel<<<dim3(NPAIR / 8, G_NUM), 256, 0, stream>>>(x, Wx, y);
  gather_kernel<<<M_NODES, 512, 0, stream>>>(y, attn, L_idx, rowstart, csr, bx, out);
}

// Round 2
// 109.801 us; speedup vs baseline: 1.9484x; 1.9484x over previous
//
#include <hip/hip_runtime.h>

#define M_NODES 4096
#define NN_NUM 16
#define G_NUM 4
#define IN_F 32
#define OUT_F 32
#define LOC_F 8
#define LHID 128
#define B_SZ 16
#define NPAIR (M_NODES * NN_NUM)       /* 65536 */
#define MM ((size_t)M_NODES * M_NODES) /* 16777216 */

// ---------------------------------------------------------------------------
// Kernel 1: fused per-pair MLP + softmax over the 16 neighbors of each node.
// attn[g*NPAIR + n], n = node*16 + neighbor (neighbors are consecutive lanes).
// ---------------------------------------------------------------------------
__global__ void attn_kernel(const float* __restrict__ maps,
                            const float* __restrict__ W1,
                            const float* __restrict__ b1,
                            const float* __restrict__ W2,
                            const float* __restrict__ b2,
                            float* __restrict__ attn) {
  const int g = blockIdx.y;
  __shared__ float sW1[LHID * LOC_F];
  __shared__ float sb1[LHID];
  __shared__ float sW2[LHID];
  const int t = threadIdx.x;
  for (int k = t; k < LHID * LOC_F; k += 256) sW1[k] = W1[g * LHID * LOC_F + k];
  if (t < LHID) { sb1[t] = b1[g * LHID + t]; sW2[t] = W2[g * LHID + t]; }
  __syncthreads();

  const int n = blockIdx.x * 256 + t;
  const float4 mA = *reinterpret_cast<const float4*>(maps + (size_t)n * LOC_F);
  const float4 mB = *reinterpret_cast<const float4*>(maps + (size_t)n * LOC_F + 4);

  float ctx = b2[g];
#pragma unroll 4
  for (int h = 0; h < LHID; ++h) {
    const float* w = &sW1[h * LOC_F];   // uniform address -> LDS broadcast
    float a = sb1[h];
    a = fmaf(w[0], mA.x, a); a = fmaf(w[1], mA.y, a);
    a = fmaf(w[2], mA.z, a); a = fmaf(w[3], mA.w, a);
    a = fmaf(w[4], mB.x, a); a = fmaf(w[5], mB.y, a);
    a = fmaf(w[6], mB.z, a); a = fmaf(w[7], mB.w, a);
    const float e = __expf(-2.0f * fabsf(a));
    const float th = __builtin_copysignf((1.0f - e) / (1.0f + e), a);
    ctx = fmaf(sW2[h], th, ctx);
  }

  // softmax across the 16 lanes of this node (lanes n..n+15 in-wave)
  float mx = ctx;
#pragma unroll
  for (int m = 8; m >= 1; m >>= 1) mx = fmaxf(mx, __shfl_xor(mx, m, 64));
  const float e = __expf(ctx - mx);
  float s = e;
#pragma unroll
  for (int m = 8; m >= 1; m >>= 1) s += __shfl_xor(s, m, 64);
  attn[(size_t)g * NPAIR + n] = e / s;
}

// ---------------------------------------------------------------------------
// Targeted clear: zero only the winner[] entries this call will touch
// (65536 scattered stores ~ 4 MB of lines, vs 64 MB full memset) + count[].
// ---------------------------------------------------------------------------
__global__ void clear_kernel(const int* __restrict__ L_idx,
                             unsigned* __restrict__ winner,
                             unsigned* __restrict__ count) {
  const int n = blockIdx.x * 256 + threadIdx.x;
  winner[(unsigned)L_idx[n]] = 0u;
  if (n < M_NODES) count[n] = 0u;
}

// Duplicate resolution: `.set` semantics = LAST occurrence wins.
__global__ void winner_kernel(const int* __restrict__ L_idx,
                              unsigned* __restrict__ winner) {
  const int n = blockIdx.x * 256 + threadIdx.x;
  atomicMax(&winner[(unsigned)L_idx[n]], (unsigned)(n + 1));
}

__global__ void hist_kernel(const int* __restrict__ L_idx,
                            const unsigned* __restrict__ winner,
                            unsigned* __restrict__ count) {
  const int n = blockIdx.x * 256 + threadIdx.x;
  const unsigned pos = (unsigned)L_idx[n];
  if (winner[pos] == (unsigned)(n + 1)) atomicAdd(&count[pos >> 12], 1u);
}

// Exclusive scan of count[4096] -> rowstart[4097]; rowfill = copy of rowstart.
__global__ void scan_kernel(const unsigned* __restrict__ count,
                            unsigned* __restrict__ rowstart,
                            unsigned* __restrict__ rowfill) {
  __shared__ unsigned sums[256];
  const int t = threadIdx.x;
  unsigned local[16];
  unsigned s = 0;
  for (int k = 0; k < 16; ++k) { local[k] = s; s += count[t * 16 + k]; }
  sums[t] = s;
  __syncthreads();
  for (int off = 1; off < 256; off <<= 1) {
    unsigned v = (t >= off) ? sums[t - off] : 0u;
    __syncthreads();
    sums[t] += v;
    __syncthreads();
  }
  const unsigned base = (t == 0) ? 0u : sums[t - 1];
  for (int k = 0; k < 16; ++k) {
    const unsigned rs = base + local[k];
    rowstart[t * 16 + k] = rs;
    rowfill[t * 16 + k] = rs;
  }
  if (t == 255) rowstart[M_NODES] = sums[255];
}

// Fill CSR: payload = column j, plus the 4 per-graph attn values (float4).
__global__ void fill_kernel(const int* __restrict__ L_idx,
                            const unsigned* __restrict__ winner,
                            const float* __restrict__ attn,
                            unsigned* __restrict__ rowfill,
                            unsigned* __restrict__ csr_j,
                            float4* __restrict__ csr_a) {
  const int n = blockIdx.x * 256 + threadIdx.x;
  const unsigned pos = (unsigned)L_idx[n];
  if (winner[pos] == (unsigned)(n + 1)) {
    const unsigned slot = atomicAdd(&rowfill[pos >> 12], 1u);
    csr_j[slot] = pos & (M_NODES - 1);
    csr_a[slot] = make_float4(attn[n], attn[NPAIR + n],
                              attn[2 * NPAIR + n], attn[3 * NPAIR + n]);
  }
}

// ---------------------------------------------------------------------------
// Transpose x (b, j, f) -> xT (j, b, f) so each nonzero's 16 batch-rows are
// one contiguous 2 KB chunk. float4-ized.
// ---------------------------------------------------------------------------
__global__ void xT_kernel(const float4* __restrict__ x4,
                          float4* __restrict__ xT4) {
  const int idx = blockIdx.x * 256 + threadIdx.x;   // [0, 524288)
  const int fq = idx & 7;
  const int b = (idx >> 3) & 15;
  const int j = idx >> 7;
  xT4[idx] = x4[((size_t)b * M_NODES + j) * 8 + fq];
}

// ---------------------------------------------------------------------------
// Fused gather + epilogue. One block per output row i, 512 threads.
// Phase 1 (t = b*32+f): acc[g] = sum_{n in row i} attn[g,n] * xT[j_n, b, f]
// Phase 2 (t = b*32+o): out[b,i,o] = bx[o] + sum_{g,f} agg[g,b,f]*Wx[g,f,o]
// ---------------------------------------------------------------------------
__global__ void gather_kernel(const float* __restrict__ xT,
                              const unsigned* __restrict__ csr_j,
                              const float4* __restrict__ csr_a,
                              const unsigned* __restrict__ rowstart,
                              const float* __restrict__ Wx,
                              const float* __restrict__ bx,
                              float* __restrict__ out) {
  __shared__ float sWx[G_NUM * IN_F * OUT_F];   // 16 KB, [g][f][o]
  __shared__ float sAgg[G_NUM * 512];           //  8 KB, [g][b*32+f]
  const int i = blockIdx.x;
  const int t = threadIdx.x;
  for (int k = t; k < G_NUM * IN_F * OUT_F; k += 512) sWx[k] = Wx[k];

  float a0 = 0.f, a1 = 0.f, a2 = 0.f, a3 = 0.f;
  const unsigned s0 = rowstart[i];
  const unsigned s1 = rowstart[i + 1];
  for (unsigned s = s0; s < s1; ++s) {
    const unsigned j = csr_j[s];        // block-uniform (L1 broadcast)
    const float4 a = csr_a[s];          // block-uniform
    const float v = xT[(size_t)j * 512 + t];  // contiguous 2 KB per nnz
    a0 = fmaf(a.x, v, a0);
    a1 = fmaf(a.y, v, a1);
    a2 = fmaf(a.z, v, a2);
    a3 = fmaf(a.w, v, a3);
  }
  sAgg[0 * 512 + t] = a0;
  sAgg[1 * 512 + t] = a1;
  sAgg[2 * 512 + t] = a2;
  sAgg[3 * 512 + t] = a3;
  __syncthreads();

  const int b = t >> 5;
  const int o = t & 31;
  float r = bx[o];
#pragma unroll
  for (int g = 0; g < G_NUM; ++g) {
    const float* A = &sAgg[g * 512 + b * 32];   // broadcast reads
    const float* W = &sWx[g * IN_F * OUT_F + o]; // bank-spread reads
#pragma unroll
    for (int f = 0; f < IN_F; ++f) r = fmaf(A[f], W[f * 32], r);
  }
  out[((size_t)b * M_NODES + i) * OUT_F + o] = r;
}

// ---------------------------------------------------------------------------
extern "C" void kernel_launch(void* const* d_in, const int* in_sizes, int n_in,
                              void* d_out, int out_size, void* d_ws, size_t ws_size,
                              hipStream_t stream) {
  const float* x    = (const float*)d_in[0];
  const float* maps = (const float*)d_in[1];
  const int*   L_idx = (const int*)d_in[2];
  const float* W1   = (const float*)d_in[3];
  const float* b1   = (const float*)d_in[4];
  const float* W2   = (const float*)d_in[5];
  const float* b2   = (const float*)d_in[6];
  const float* Wx   = (const float*)d_in[7];
  const float* bx   = (const float*)d_in[8];
  float* out = (float*)d_out;

  // workspace layout
  float* attn = (float*)d_ws;                                    // 1 MB
  float* xT = attn + (size_t)G_NUM * NPAIR;                      // 8 MB
  unsigned* winner = (unsigned*)(xT + (size_t)M_NODES * B_SZ * IN_F); // 64 MB
  unsigned* count = winner + MM;                                 // 16 KB
  unsigned* rowstart = count + M_NODES;                          // 4097 u32
  unsigned* rowfill = rowstart + (M_NODES + 1);                  // 4096 u32
  unsigned* csr_j = rowfill + M_NODES;                           // 256 KB
  float4* csr_a = (float4*)(csr_j + NPAIR);                      // 1 MB (16B aligned: offsets all x16)

  clear_kernel<<<NPAIR / 256, 256, 0, stream>>>(L_idx, winner, count);
  attn_kernel<<<dim3(NPAIR / 256, G_NUM), 256, 0, stream>>>(maps, W1, b1, W2, b2, attn);
  xT_kernel<<<(M_NODES * B_SZ * IN_F / 4) / 256, 256, 0, stream>>>(
      (const float4*)x, (float4*)xT);
  winner_kernel<<<NPAIR / 256, 256, 0, stream>>>(L_idx, winner);
  hist_kernel<<<NPAIR / 256, 256, 0, stream>>>(L_idx, winner, count);
  scan_kernel<<<1, 256, 0, stream>>>(count, rowstart, rowfill);
  fill_kernel<<<NPAIR / 256, 256, 0, stream>>>(L_idx, winner, attn, rowfill, csr_j, csr_a);
  gather_kernel<<<M_NODES, 512, 0, stream>>>(xT, csr_j, csr_a, rowstart, Wx, bx, out);
}

// Round 3
// 81.128 us; speedup vs baseline: 2.6371x; 1.3534x over previous
//
#include <hip/hip_runtime.h>

#define M_NODES 4096
#define NN_NUM 16
#define G_NUM 4
#define IN_F 32
#define OUT_F 32
#define LOC_F 8
#define LHID 128
#define B_SZ 16
#define NPAIR 65536
#define ROWCAP 64

// ---------------------------------------------------------------------------
// K1: fused {attn MLP+softmax} + {xT transpose} + {winner/rowcount clears}.
// Grid dim3(256, G_NUM) x 256 threads; block (bx, g) handles n = bx*256+t.
// ---------------------------------------------------------------------------
__global__ void prep_kernel(const float4* __restrict__ x4,
                            const float* __restrict__ maps,
                            const int* __restrict__ L_idx,
                            const float* __restrict__ W1,
                            const float* __restrict__ b1,
                            const float* __restrict__ W2,
                            const float* __restrict__ b2,
                            float* __restrict__ attn,
                            float4* __restrict__ xT4,
                            unsigned* __restrict__ winner,
                            unsigned* __restrict__ rowcount) {
  const int g = blockIdx.y;
  const int t = threadIdx.x;
  const int n = blockIdx.x * 256 + t;

  __shared__ float sW1[LHID * LOC_F];
  __shared__ float sb1[LHID];
  __shared__ float sW2[LHID];
  for (int k = t; k < LHID * LOC_F; k += 256) sW1[k] = W1[g * LHID * LOC_F + k];
  if (t < LHID) { sb1[t] = b1[g * LHID + t]; sW2[t] = W2[g * LHID + t]; }

  // Independent work overlapped with weight staging:
  if (g == 0) {
    winner[(unsigned)L_idx[n]] = 0u;       // targeted clear (dups benign)
    if (n < M_NODES) rowcount[n] = 0u;
  }
  {
    // xT[j][b][f] <- x[b][j][f]; 524288 float4 over 262144 threads (2 each)
    const int idx0 = (g << 16) | n;
#pragma unroll
    for (int k = 0; k < 2; ++k) {
      const int idx = idx0 + k * 262144;
      const int fq = idx & 7;
      const int b = (idx >> 3) & 15;
      const int j = idx >> 7;
      xT4[idx] = x4[((size_t)(b * M_NODES + j)) * 8 + fq];
    }
  }
  __syncthreads();

  const float4 mA = *reinterpret_cast<const float4*>(maps + (size_t)n * LOC_F);
  const float4 mB = *reinterpret_cast<const float4*>(maps + (size_t)n * LOC_F + 4);

  float ctx = b2[g];
#pragma unroll 4
  for (int h = 0; h < LHID; ++h) {
    const float* w = &sW1[h * LOC_F];   // uniform address -> LDS broadcast
    float a = sb1[h];
    a = fmaf(w[0], mA.x, a); a = fmaf(w[1], mA.y, a);
    a = fmaf(w[2], mA.z, a); a = fmaf(w[3], mA.w, a);
    a = fmaf(w[4], mB.x, a); a = fmaf(w[5], mB.y, a);
    a = fmaf(w[6], mB.z, a); a = fmaf(w[7], mB.w, a);
    const float e = __expf(-2.0f * fabsf(a));
    const float th = __builtin_copysignf((1.0f - e) / (1.0f + e), a);
    ctx = fmaf(sW2[h], th, ctx);
  }

  // softmax across the 16 lanes of this node (lanes are in-wave)
  float mx = ctx;
#pragma unroll
  for (int m = 8; m >= 1; m >>= 1) mx = fmaxf(mx, __shfl_xor(mx, m, 64));
  const float e = __expf(ctx - mx);
  float s = e;
#pragma unroll
  for (int m = 8; m >= 1; m >>= 1) s += __shfl_xor(s, m, 64);
  attn[(size_t)g * NPAIR + n] = e / s;
}

// ---------------------------------------------------------------------------
// K2: winner atomicMax + CSR fill in ONE kernel (fill does not read winner;
// the dedup check moves to gather). Fixed 64 slots per row, no scan needed.
// ---------------------------------------------------------------------------
__global__ void fill_kernel(const int* __restrict__ L_idx,
                            const float* __restrict__ attn,
                            unsigned* __restrict__ winner,
                            unsigned* __restrict__ rowcount,
                            uint2* __restrict__ csr_jn,
                            float4* __restrict__ csr_a) {
  const int n = blockIdx.x * 256 + threadIdx.x;
  const unsigned pos = (unsigned)L_idx[n];
  const unsigned i = pos >> 12;
  const unsigned j = pos & (M_NODES - 1);
  atomicMax(&winner[pos], (unsigned)(n + 1));
  const float4 a = make_float4(attn[n], attn[NPAIR + n],
                               attn[2 * NPAIR + n], attn[3 * NPAIR + n]);
  const unsigned slot = atomicAdd(&rowcount[i], 1u);
  if (slot < ROWCAP) {
    csr_jn[(size_t)i * ROWCAP + slot] = make_uint2(j, (unsigned)n);
    csr_a[(size_t)i * ROWCAP + slot] = a;
  }
}

// ---------------------------------------------------------------------------
// K3: gather + epilogue. 512 blocks x 256 threads; block handles 8 rows.
// Phase 0: stage this block's CSR entries + winner masks into LDS (parallel
//          scattered loads, once). Pull Wx columns into registers.
// Per row: thread t accumulates agg for vector elements t and t+256
//          (t = b*32+f view), then epilogue thread t = (b,o) view computes
//          out via register-held Wx + float4 LDS broadcasts.
// ---------------------------------------------------------------------------
__global__ void __launch_bounds__(256, 2)
gather_kernel(const float* __restrict__ xT,
              const uint2* __restrict__ csr_jn,
              const float4* __restrict__ csr_a,
              const unsigned* __restrict__ rowcount,
              const unsigned* __restrict__ winner,
              const float* __restrict__ Wx,
              const float* __restrict__ bxp,
              float* __restrict__ out) {
  __shared__ float ldsw[G_NUM * IN_F * OUT_F];  // 16 KB: Wx stage -> sAgg reuse
  __shared__ unsigned sJ[8 * ROWCAP];           // 2 KB
  __shared__ float4 sQ[8 * ROWCAP];             // 8 KB (winner-masked attn)
  __shared__ unsigned sCnt[8];

  const int t = threadIdx.x;
  const int i0 = blockIdx.x * 8;

  // stage Wx (coalesced) + CSR entries + winner masks
  for (int k = t; k < G_NUM * IN_F * OUT_F; k += 256) ldsw[k] = Wx[k];
  if (t < 8) sCnt[t] = min(rowcount[i0 + t], (unsigned)ROWCAP);
#pragma unroll
  for (int q = 0; q < 2; ++q) {
    const int slot = t + q * 256;
    const int row = slot >> 6;
    const int i = i0 + row;
    const uint2 e = csr_jn[(size_t)i * ROWCAP + (slot & 63)];
    const float4 a = csr_a[(size_t)i * ROWCAP + (slot & 63)];
    const unsigned j = e.x & (M_NODES - 1);   // bound stale slots
    const float m =
        (winner[(size_t)i * M_NODES + j] == e.y + 1u) ? 1.0f : 0.0f;
    sJ[slot] = j;
    sQ[slot] = make_float4(a.x * m, a.y * m, a.z * m, a.w * m);
  }
  __syncthreads();

  // pull Wx columns into registers: w[g][f] = Wx[g][f][o]
  const int b0 = t >> 5;       // 0..7
  const int o = t & 31;
  float w[G_NUM][IN_F];
#pragma unroll
  for (int g = 0; g < G_NUM; ++g)
#pragma unroll
    for (int f = 0; f < IN_F; ++f) w[g][f] = ldsw[g * 1024 + f * 32 + o];
  const float bias = bxp[o];
  __syncthreads();  // ldsw free for sAgg reuse

  for (int r = 0; r < 8; ++r) {
    const int i = i0 + r;
    const unsigned cnt = sCnt[r];
    const unsigned base = r * ROWCAP;
    float a0 = 0.f, a1 = 0.f, a2 = 0.f, a3 = 0.f;
    float c0 = 0.f, c1 = 0.f, c2 = 0.f, c3 = 0.f;
    unsigned s = 0;
    for (; s + 4 <= cnt; s += 4) {
      const unsigned j0 = sJ[base + s],     j1 = sJ[base + s + 1];
      const unsigned j2 = sJ[base + s + 2], j3 = sJ[base + s + 3];
      const float4 q0 = sQ[base + s],     q1 = sQ[base + s + 1];
      const float4 q2 = sQ[base + s + 2], q3 = sQ[base + s + 3];
      const float* p0 = xT + (size_t)j0 * 512;
      const float* p1 = xT + (size_t)j1 * 512;
      const float* p2 = xT + (size_t)j2 * 512;
      const float* p3 = xT + (size_t)j3 * 512;
      const float v0 = p0[t], u0 = p0[t + 256];
      const float v1 = p1[t], u1 = p1[t + 256];
      const float v2 = p2[t], u2 = p2[t + 256];
      const float v3 = p3[t], u3 = p3[t + 256];
      a0 = fmaf(q0.x, v0, a0); a1 = fmaf(q0.y, v0, a1);
      a2 = fmaf(q0.z, v0, a2); a3 = fmaf(q0.w, v0, a3);
      c0 = fmaf(q0.x, u0, c0); c1 = fmaf(q0.y, u0, c1);
      c2 = fmaf(q0.z, u0, c2); c3 = fmaf(q0.w, u0, c3);
      a0 = fmaf(q1.x, v1, a0); a1 = fmaf(q1.y, v1, a1);
      a2 = fmaf(q1.z, v1, a2); a3 = fmaf(q1.w, v1, a3);
      c0 = fmaf(q1.x, u1, c0); c1 = fmaf(q1.y, u1, c1);
      c2 = fmaf(q1.z, u1, c2); c3 = fmaf(q1.w, u1, c3);
      a0 = fmaf(q2.x, v2, a0); a1 = fmaf(q2.y, v2, a1);
      a2 = fmaf(q2.z, v2, a2); a3 = fmaf(q2.w, v2, a3);
      c0 = fmaf(q2.x, u2, c0); c1 = fmaf(q2.y, u2, c1);
      c2 = fmaf(q2.z, u2, c2); c3 = fmaf(q2.w, u2, c3);
      a0 = fmaf(q3.x, v3, a0); a1 = fmaf(q3.y, v3, a1);
      a2 = fmaf(q3.z, v3, a2); a3 = fmaf(q3.w, v3, a3);
      c0 = fmaf(q3.x, u3, c0); c1 = fmaf(q3.y, u3, c1);
      c2 = fmaf(q3.z, u3, c2); c3 = fmaf(q3.w, u3, c3);
    }
    for (; s < cnt; ++s) {
      const unsigned j0 = sJ[base + s];
      const float4 q0 = sQ[base + s];
      const float* p0 = xT + (size_t)j0 * 512;
      const float v0 = p0[t], u0 = p0[t + 256];
      a0 = fmaf(q0.x, v0, a0); a1 = fmaf(q0.y, v0, a1);
      a2 = fmaf(q0.z, v0, a2); a3 = fmaf(q0.w, v0, a3);
      c0 = fmaf(q0.x, u0, c0); c1 = fmaf(q0.y, u0, c1);
      c2 = fmaf(q0.z, u0, c2); c3 = fmaf(q0.w, u0, c3);
    }

    // hand off agg through LDS: [g][elem] where elem = b*32+f
    ldsw[0 * 512 + t] = a0; ldsw[1 * 512 + t] = a1;
    ldsw[2 * 512 + t] = a2; ldsw[3 * 512 + t] = a3;
    ldsw[0 * 512 + t + 256] = c0; ldsw[1 * 512 + t + 256] = c1;
    ldsw[2 * 512 + t + 256] = c2; ldsw[3 * 512 + t + 256] = c3;
    __syncthreads();

    // epilogue: out[b,i,o] = bias + sum_{g,f} agg[g,b,f] * w[g][f]
    float r0 = bias, r1 = bias;
#pragma unroll
    for (int g = 0; g < G_NUM; ++g) {
      const float* A0 = &ldsw[g * 512 + b0 * 32];
      const float* A1 = A0 + 256;  // b0+8
#pragma unroll
      for (int fq = 0; fq < 8; ++fq) {
        const float4 xa = *reinterpret_cast<const float4*>(A0 + fq * 4);
        const float4 xb = *reinterpret_cast<const float4*>(A1 + fq * 4);
        r0 = fmaf(xa.x, w[g][fq * 4 + 0], r0);
        r0 = fmaf(xa.y, w[g][fq * 4 + 1], r0);
        r0 = fmaf(xa.z, w[g][fq * 4 + 2], r0);
        r0 = fmaf(xa.w, w[g][fq * 4 + 3], r0);
        r1 = fmaf(xb.x, w[g][fq * 4 + 0], r1);
        r1 = fmaf(xb.y, w[g][fq * 4 + 1], r1);
        r1 = fmaf(xb.z, w[g][fq * 4 + 2], r1);
        r1 = fmaf(xb.w, w[g][fq * 4 + 3], r1);
      }
    }
    out[((size_t)b0 * M_NODES + i) * OUT_F + o] = r0;
    out[((size_t)(b0 + 8) * M_NODES + i) * OUT_F + o] = r1;
    __syncthreads();  // before next row overwrites ldsw
  }
}

// ---------------------------------------------------------------------------
extern "C" void kernel_launch(void* const* d_in, const int* in_sizes, int n_in,
                              void* d_out, int out_size, void* d_ws, size_t ws_size,
                              hipStream_t stream) {
  const float* x    = (const float*)d_in[0];
  const float* maps = (const float*)d_in[1];
  const int*   L_idx = (const int*)d_in[2];
  const float* W1   = (const float*)d_in[3];
  const float* b1   = (const float*)d_in[4];
  const float* W2   = (const float*)d_in[5];
  const float* b2   = (const float*)d_in[6];
  const float* Wx   = (const float*)d_in[7];
  const float* bx   = (const float*)d_in[8];
  float* out = (float*)d_out;

  // workspace layout (element offsets; csr_a ends up 16B-aligned)
  float* attn = (float*)d_ws;                                     //  1 MB
  float* xT = attn + (size_t)G_NUM * NPAIR;                       //  8 MB
  unsigned* winner = (unsigned*)(xT + (size_t)M_NODES * B_SZ * IN_F); // 64 MB
  unsigned* rowcount = winner + (size_t)M_NODES * M_NODES;        // 16 KB
  uint2* csr_jn = (uint2*)(rowcount + M_NODES);                   //  2 MB
  float4* csr_a = (float4*)(csr_jn + (size_t)M_NODES * ROWCAP);   //  4 MB

  prep_kernel<<<dim3(256, G_NUM), 256, 0, stream>>>(
      (const float4*)x, maps, L_idx, W1, b1, W2, b2, attn, (float4*)xT,
      winner, rowcount);
  fill_kernel<<<NPAIR / 256, 256, 0, stream>>>(L_idx, attn, winner, rowcount,
                                               csr_jn, csr_a);
  gather_kernel<<<M_NODES / 8, 256, 0, stream>>>(xT, csr_jn, csr_a, rowcount,
                                                 winner, Wx, bx, out);
}